// Round 22
// baseline (350.414 us; speedup 1.0000x reference)
//
#include <hip/hip_runtime.h>
#include <hip/hip_bf16.h>

typedef __attribute__((ext_vector_type(8))) short bf16x8;
typedef __attribute__((ext_vector_type(4))) float f32x4;
typedef __attribute__((ext_vector_type(2))) unsigned long long u64x2;

#define WS_QKV   0          // 384 KiB: qkv frags (48 rt * 8 ks * 1024B), q-rows prescaled
#define WS_PROJ  393216     // 128 KiB: proj frags (16 rt * 8 ks * 1024B)
#define WS_MB    524288     // 8 MiB: mb[w][h][64][64] f32 = (mask[w]+bias[h])*log2e
#define WS_QB    8912896    // 3 KiB: qkvb_s[768] (q part prescaled by scale*log2e)

#define QSCALE 0.17677669529663687f   // 1/sqrt(32)
#define LOG2E  1.4426950408889634f

// RNE f32->bf16 (paired-convert path; R17-verified numerically identical)
__device__ __forceinline__ unsigned long long pack4bf(f32x4 v) {
  __hip_bfloat162 lo = __float22bfloat162_rn(float2{v[0], v[1]});
  __hip_bfloat162 hi = __float22bfloat162_rn(float2{v[2], v[3]});
  unsigned long long a = ((unsigned)__bfloat16_as_ushort(lo.x)) |
                         ((unsigned)__bfloat16_as_ushort(lo.y) << 16);
  unsigned long long b = ((unsigned)__bfloat16_as_ushort(hi.x)) |
                         ((unsigned)__bfloat16_as_ushort(hi.y) << 16);
  return (b << 32) | a;
}

// frag(rt,ks): lane l holds W[16*rt + (l&15)][32*ks + 8*(l>>4) + i], i=0..7 (bf16)
__global__ void prep_weights(const float* __restrict__ qkv_w,
                             const float* __restrict__ proj_w,
                             unsigned char* __restrict__ ws) {
  int g = blockIdx.x;   // 0..511
  int l = threadIdx.x;  // 0..63
  int lr = l & 15, lg = l >> 4;
  const float* src;
  float sc = 1.f;
  if (g < 384) {
    int rt = g >> 3, ks = g & 7;
    src = qkv_w + (size_t)(16 * rt + lr) * 256 + 32 * ks + 8 * lg;
    if (rt < 16) sc = QSCALE * LOG2E;  // fold scale and log2e into q rows
  } else {
    int p = g - 384;
    int rt = p >> 3, ks = p & 7;
    src = proj_w + (size_t)(16 * rt + lr) * 256 + 32 * ks + 8 * lg;
  }
  f32x4 a = *(const f32x4*)(src)*sc;
  f32x4 b = *(const f32x4*)(src + 4) * sc;
  unsigned long long* dst = (unsigned long long*)(ws + (size_t)g * 1024 + l * 16);
  dst[0] = pack4bf(a);
  dst[1] = pack4bf(b);
}

// mb[w][h][64][64] = (mask + rel-pos bias) * log2e, masked cols -> -1e30
__global__ void prep_aux(const float* __restrict__ mask,
                         const float* __restrict__ bias_table,
                         const float* __restrict__ qkv_b,
                         unsigned char* __restrict__ ws) {
  int bid = blockIdx.x, tid = threadIdx.x;
  if (bid < 512) {
    int w = bid >> 3, h = bid & 7;
    float* dst = (float*)(ws + WS_MB) + (size_t)bid * 4096;
    for (int it = 0; it < 16; ++it) {
      int idx = it * 256 + tid;
      int m = idx >> 6, j = idx & 63;
      float v;
      if (j >= 49) {
        v = -1e30f;
      } else {
        float bi = 0.f, mk = 0.f;
        if (m < 49) {
          int rm = m / 7, cm = m % 7, rj = j / 7, cj = j % 7;
          int rpi = (rm - rj + 6) * 13 + (cm - cj + 6);
          bi = bias_table[rpi * 8 + h];
          mk = mask[((size_t)w * 49 + m) * 49 + j];
        }
        v = (mk + bi) * LOG2E;
      }
      dst[idx] = v;
    }
  } else {  // qkv bias: q part prescaled
    float* dst = (float*)(ws + WS_QB);
    for (int i = tid; i < 768; i += 256)
      dst[i] = qkv_b[i] * (i < 256 ? QSCALE * LOG2E : 1.f);
  }
}

// One block = one window, 4 waves (256 thr), 4 passes of 2 heads.
// Wave wv: head-slot hs = wv>>1, m-half s = wv&1; pass p: head h = 2p + hs.
// x fragments in REGISTERS (xf[2][8]); ONE barrier per pass (R15 induction).
// R18 form: split-K Phase B + dual bufP slots. R22 adds T5 s_setprio(1)
// around MFMA clusters: 2 INDEPENDENT blocks/CU sit at different phases
// (one staging, one in attention) -> scheduler can favor the MFMA-entering
// wave (guide m191 regime: +4-7% attn; m190's lockstep null doesn't apply
// since cross-block waves are unsynced).
// LDS 79.5 KiB -> 2 blocks/CU (2x81408 = 159K <= 160K).
//  [0,32K)   aoR: ao[m<49][256ch] bf16, byte = m*512 + (2c ^ ((m&7)<<4));
//            rows 50..63 host per-wave bufPA = 25600 + wv*1152
//  q:  32768 + hs*4608            ([64m][32d] stride 72, wave-private rows)
//  k:  41984 + (2hs+par)*4608     ([64m][32d] stride 72)
//  vT: 60416 + (2hs+par)*4096     ([32d][64tok] stride 128)
//  bufPB: 76800 + wv*1152         (second P slot, [16m][32j] stride 72)
__global__ __launch_bounds__(256, 2)
void winattn_main(const float* __restrict__ x,
                  const unsigned char* __restrict__ ws,
                  const float* __restrict__ proj_b,
                  float* __restrict__ out) {
  __shared__ __align__(16) unsigned char lds[81408];
  const int tid = threadIdx.x;
  const int wv = tid >> 6, ln = tid & 63;
  const int lr = ln & 15, lg = ln >> 4;
  const int b = blockIdx.x;
  const int w = b & 63;
  const int hs = wv >> 1, s = wv & 1;
  const float* qbs = (const float*)(ws + WS_QB);
  unsigned char* aoR = lds;
  unsigned char* bufPA = lds + 25600 + wv * 1152;  // aoR rows 50..63
  unsigned char* bufPB = lds + 76800 + wv * 1152;
  unsigned char* qbuf = lds + 32768 + hs * 4608;

  // ---- x fragments -> registers (held for entire kernel); rows >= 49 zero
  bf16x8 xf[2][8];
#pragma unroll
  for (int ti = 0; ti < 2; ++ti) {
    const int row = 16 * (2 * s + ti) + lr;
    const float* xr = x + ((size_t)b * 49 + row) * 256 + 8 * lg;
    const bool val = (row < 49);
#pragma unroll
    for (int ks = 0; ks < 8; ++ks) {
      f32x4 va = {0.f, 0.f, 0.f, 0.f}, vb = {0.f, 0.f, 0.f, 0.f};
      if (val) {
        va = *(const f32x4*)(xr + 32 * ks);
        vb = *(const f32x4*)(xr + 32 * ks + 4);
      }
      u64x2 t2 = {pack4bf(va), pack4bf(vb)};
      xf[ti][ks] = __builtin_bit_cast(bf16x8, t2);
    }
  }

  for (int p = 0; p < 4; ++p) {
    const int par = p & 1;
    unsigned char* kbuf = lds + 41984 + (2 * hs + par) * 4608;
    unsigned char* vbuf = lds + 60416 + (2 * hs + par) * 4096;
    const int h = 2 * p + hs;
    const float* mbp = (const float*)(ws + WS_MB) + ((size_t)(w * 8 + h)) * 4096;

    // ---- prefetch mb rows for Phase C (latency hides under Phase B MFMAs)
    f32x4 mkr[4][2];
#pragma unroll
    for (int i = 0; i < 2; ++i) {
      const int m = lr + 32 * s + 16 * i;
#pragma unroll
      for (int jt = 0; jt < 4; ++jt)
        mkr[jt][i] = *(const f32x4*)(mbp + m * 64 + 16 * jt + 4 * lg);
    }

    // ---- Phase B: weight groups g=0..5 (q0,q1,k0,k1,v0,v1), double-buffered
    bf16x8 afb[2][8];
#pragma unroll
    for (int ks = 0; ks < 8; ++ks)
      afb[0][ks] = *(const bf16x8*)(ws + (size_t)((2 * h) * 8 + ks) * 1024 + ln * 16);

    // q,k groups (g = 0..3); split-K: two independent 4-deep chains per ti
#pragma unroll
    for (int g = 0; g < 4; ++g) {
      const int pp = g >> 1, g2 = g & 1;
      {  // prefetch group g+1
        const int gn = g + 1;
        const int rtn = 16 * (gn >> 1) + 2 * h + (gn & 1);
#pragma unroll
        for (int ks = 0; ks < 8; ++ks)
          afb[gn & 1][ks] = *(const bf16x8*)(ws + (size_t)(rtn * 8 + ks) * 1024 + ln * 16);
      }
      f32x4 cc = *(const f32x4*)(qbs + pp * 256 + 32 * h + 16 * g2 + 4 * lg);
      unsigned char* dst = (pp == 0 ? qbuf : kbuf);
#pragma unroll
      for (int ti = 0; ti < 2; ++ti) {
        const int row = 16 * (2 * s + ti) + lr;
        f32x4 a0 = cc, a1 = {0.f, 0.f, 0.f, 0.f};
        __builtin_amdgcn_s_setprio(1);
#pragma unroll
        for (int kk = 0; kk < 4; ++kk) {
          a0 = __builtin_amdgcn_mfma_f32_16x16x32_bf16(afb[g & 1][kk], xf[ti][kk], a0, 0, 0, 0);
          a1 = __builtin_amdgcn_mfma_f32_16x16x32_bf16(afb[g & 1][kk + 4], xf[ti][kk + 4], a1, 0, 0, 0);
        }
        __builtin_amdgcn_s_setprio(0);
        a0 += a1;
        *(unsigned long long*)(dst + row * 72 + 32 * g2 + 8 * lg) = pack4bf(a0);
      }
    }
    bf16x8 qf[2];
#pragma unroll
    for (int i = 0; i < 2; ++i)  // own rows (wave-private) -> no barrier
      qf[i] = *(const bf16x8*)(qbuf + (lr + 32 * s + 16 * i) * 72 + 16 * lg);

    // v groups (g = 4,5) -> vT into vbuf; same split-K
#pragma unroll
    for (int g = 4; g < 6; ++g) {
      const int g2 = g & 1;
      if (g < 5) {  // prefetch group 5
#pragma unroll
        for (int ks = 0; ks < 8; ++ks)
          afb[1][ks] = *(const bf16x8*)(ws + (size_t)((32 + 2 * h + 1) * 8 + ks) * 1024 + ln * 16);
      }
      const float vb = qbs[512 + 32 * h + 16 * g2 + lr];
      f32x4 cc = {vb, vb, vb, vb};
#pragma unroll
      for (int ti = 0; ti < 2; ++ti) {
        const int t = 2 * s + ti;
        f32x4 a0 = cc, a1 = {0.f, 0.f, 0.f, 0.f};
        __builtin_amdgcn_s_setprio(1);
#pragma unroll
        for (int kk = 0; kk < 4; ++kk) {
          a0 = __builtin_amdgcn_mfma_f32_16x16x32_bf16(xf[ti][kk], afb[g & 1][kk], a0, 0, 0, 0);
          a1 = __builtin_amdgcn_mfma_f32_16x16x32_bf16(xf[ti][kk + 4], afb[g & 1][kk + 4], a1, 0, 0, 0);
        }
        __builtin_amdgcn_s_setprio(0);
        a0 += a1;
        const int d = 16 * g2 + lr;
        *(unsigned long long*)(vbuf + d * 128 + ((32 * t + 8 * lg) ^ ((d & 7) << 4))) =
            pack4bf(a0);
      }
    }
    __syncthreads();  // the ONE barrier: k + vT staged pair-wide
    bf16x8 kf[4];
#pragma unroll
    for (int t = 0; t < 4; ++t)
      kf[t] = *(const bf16x8*)(kbuf + (lr + 16 * t) * 72 + 16 * lg);

    // ---- Phase C: batched QK->stores (both i, dual bufP), then both PV
    float sm[2] = {0.f, 0.f};
    f32x4 oacc[2][2];
#pragma unroll
    for (int dt = 0; dt < 2; ++dt)
#pragma unroll
      for (int i = 0; i < 2; ++i) oacc[dt][i] = {0.f, 0.f, 0.f, 0.f};
#pragma unroll
    for (int jh = 0; jh < 2; ++jh) {
      bf16x8 vf[2];
#pragma unroll
      for (int dt = 0; dt < 2; ++dt) {
        const int d = lr + 16 * dt;
        vf[dt] = *(const bf16x8*)(vbuf + d * 128 + ((64 * jh + 16 * lg) ^ ((d & 7) << 4)));
      }
#pragma unroll
      for (int i = 0; i < 2; ++i) {
        unsigned char* bp = (i == 0) ? bufPA : bufPB;
#pragma unroll
        for (int jt2 = 0; jt2 < 2; ++jt2) {
          const int jt = 2 * jh + jt2;
          __builtin_amdgcn_s_setprio(1);
          f32x4 sv = __builtin_amdgcn_mfma_f32_16x16x32_bf16(kf[jt], qf[i], mkr[jt][i], 0, 0, 0);
          __builtin_amdgcn_s_setprio(0);
#pragma unroll
          for (int r2 = 0; r2 < 4; ++r2) {
            float e = __builtin_amdgcn_exp2f(sv[r2]);
            sv[r2] = e;
            sm[i] += e;
          }
          *(unsigned long long*)(bp + lr * 72 + 32 * jt2 + 8 * lg) = pack4bf(sv);
        }
      }
#pragma unroll
      for (int i = 0; i < 2; ++i) {
        unsigned char* bp = (i == 0) ? bufPA : bufPB;
        bf16x8 pf = *(const bf16x8*)(bp + lr * 72 + 16 * lg);
        __builtin_amdgcn_s_setprio(1);
#pragma unroll
        for (int dt = 0; dt < 2; ++dt)
          oacc[dt][i] = __builtin_amdgcn_mfma_f32_16x16x32_bf16(vf[dt], pf, oacc[dt][i], 0, 0, 0);
        __builtin_amdgcn_s_setprio(0);
      }
    }
    // normalize + write ao (rows m<49 only; rows 50..63 host bufPA)
#pragma unroll
    for (int i = 0; i < 2; ++i) {
      float t = sm[i];
      t += __shfl_xor(t, 16);
      t += __shfl_xor(t, 32);
      const float inv = 1.f / t;
      const int m = lr + 32 * s + 16 * i;
      if (m < 49) {
#pragma unroll
        for (int dt = 0; dt < 2; ++dt)
          *(unsigned long long*)(aoR + m * 512 +
                                 ((64 * h + 32 * dt + 8 * lg) ^ ((m & 7) << 4))) =
              pack4bf(oacc[dt][i] * inv);
      }
    }
  }
  __syncthreads();  // all heads' ao staged

  // ---- Phase D: proj^T[o][m] = sum_c Wp[o][c] * ao[m][c]
  // i2-outer: 4 weight-tile loads (double-buffered); aof from LDS
  const unsigned char* wsP = ws + WS_PROJ;
  bf16x8 afD[2][8];
#pragma unroll
  for (int ks = 0; ks < 8; ++ks)
    afD[0][ks] = *(const bf16x8*)(wsP + (size_t)((4 * wv) * 8 + ks) * 1024 + ln * 16);
#pragma unroll
  for (int i2 = 0; i2 < 4; ++i2) {
    const int mt = 4 * wv + i2;
    if (i2 < 3) {
#pragma unroll
      for (int ks = 0; ks < 8; ++ks)
        afD[(i2 + 1) & 1][ks] =
            *(const bf16x8*)(wsP + (size_t)((mt + 1) * 8 + ks) * 1024 + ln * 16);
    }
    const f32x4 pb = *(const f32x4*)(proj_b + 16 * mt + 4 * lg);
#pragma unroll
    for (int tt = 0; tt < 4; ++tt) {
      const int m = lr + 16 * tt;
      f32x4 acc = {0.f, 0.f, 0.f, 0.f};
      __builtin_amdgcn_s_setprio(1);
#pragma unroll
      for (int ks = 0; ks < 8; ++ks) {
        bf16x8 aof = *(const bf16x8*)(aoR + m * 512 + ((64 * ks + 16 * lg) ^ ((m & 7) << 4)));
        acc = __builtin_amdgcn_mfma_f32_16x16x32_bf16(afD[i2 & 1][ks], aof, acc, 0, 0, 0);
      }
      __builtin_amdgcn_s_setprio(0);
      if (m < 49) {
        *(f32x4*)(out + ((size_t)b * 49 + m) * 256 + 16 * mt + 4 * lg) = acc + pb;
      }
    }
  }
}

extern "C" void kernel_launch(void* const* d_in, const int* in_sizes, int n_in,
                              void* d_out, int out_size, void* d_ws, size_t ws_size,
                              hipStream_t stream) {
  const float* x = (const float*)d_in[0];
  const float* mask = (const float*)d_in[1];
  const float* qkv_w = (const float*)d_in[2];
  const float* qkv_b = (const float*)d_in[3];
  const float* proj_w = (const float*)d_in[4];
  const float* proj_b = (const float*)d_in[5];
  const float* bias_table = (const float*)d_in[6];
  unsigned char* ws = (unsigned char*)d_ws;
  float* out = (float*)d_out;

  prep_weights<<<512, 64, 0, stream>>>(qkv_w, proj_w, ws);
  prep_aux<<<513, 256, 0, stream>>>(mask, bias_table, qkv_b, ws);
  winattn_main<<<4096, 256, 0, stream>>>(x, ws, proj_b, out);
}

// Round 23
// 298.743 us; speedup vs baseline: 1.1730x; 1.1730x over previous
//
#include <hip/hip_runtime.h>
#include <hip/hip_bf16.h>

typedef __attribute__((ext_vector_type(8))) short bf16x8;
typedef __attribute__((ext_vector_type(4))) float f32x4;
typedef __attribute__((ext_vector_type(2))) unsigned long long u64x2;

#define WS_QKV   0          // 384 KiB: qkv frags (48 rt * 8 ks * 1024B), q-rows prescaled
#define WS_PROJ  393216     // 128 KiB: proj frags (16 rt * 8 ks * 1024B)
#define WS_MB    524288     // 8 MiB: mb[w][h][64][64] f32 = (mask[w]+bias[h])*log2e
#define WS_QB    8912896    // 3 KiB: qkvb_s[768] (q part prescaled by scale*log2e)

#define QSCALE 0.17677669529663687f   // 1/sqrt(32)
#define LOG2E  1.4426950408889634f

// RNE f32->bf16 (paired-convert path; R17-verified numerically identical)
__device__ __forceinline__ unsigned long long pack4bf(f32x4 v) {
  __hip_bfloat162 lo = __float22bfloat162_rn(float2{v[0], v[1]});
  __hip_bfloat162 hi = __float22bfloat162_rn(float2{v[2], v[3]});
  unsigned long long a = ((unsigned)__bfloat16_as_ushort(lo.x)) |
                         ((unsigned)__bfloat16_as_ushort(lo.y) << 16);
  unsigned long long b = ((unsigned)__bfloat16_as_ushort(hi.x)) |
                         ((unsigned)__bfloat16_as_ushort(hi.y) << 16);
  return (b << 32) | a;
}

// frag(rt,ks): lane l holds W[16*rt + (l&15)][32*ks + 8*(l>>4) + i], i=0..7 (bf16)
__global__ void prep_weights(const float* __restrict__ qkv_w,
                             const float* __restrict__ proj_w,
                             unsigned char* __restrict__ ws) {
  int g = blockIdx.x;   // 0..511
  int l = threadIdx.x;  // 0..63
  int lr = l & 15, lg = l >> 4;
  const float* src;
  float sc = 1.f;
  if (g < 384) {
    int rt = g >> 3, ks = g & 7;
    src = qkv_w + (size_t)(16 * rt + lr) * 256 + 32 * ks + 8 * lg;
    if (rt < 16) sc = QSCALE * LOG2E;  // fold scale and log2e into q rows
  } else {
    int p = g - 384;
    int rt = p >> 3, ks = p & 7;
    src = proj_w + (size_t)(16 * rt + lr) * 256 + 32 * ks + 8 * lg;
  }
  f32x4 a = *(const f32x4*)(src)*sc;
  f32x4 b = *(const f32x4*)(src + 4) * sc;
  unsigned long long* dst = (unsigned long long*)(ws + (size_t)g * 1024 + l * 16);
  dst[0] = pack4bf(a);
  dst[1] = pack4bf(b);
}

// mb[w][h][64][64] = (mask + rel-pos bias) * log2e, masked cols -> -1e30
__global__ void prep_aux(const float* __restrict__ mask,
                         const float* __restrict__ bias_table,
                         const float* __restrict__ qkv_b,
                         unsigned char* __restrict__ ws) {
  int bid = blockIdx.x, tid = threadIdx.x;
  if (bid < 512) {
    int w = bid >> 3, h = bid & 7;
    float* dst = (float*)(ws + WS_MB) + (size_t)bid * 4096;
    for (int it = 0; it < 16; ++it) {
      int idx = it * 256 + tid;
      int m = idx >> 6, j = idx & 63;
      float v;
      if (j >= 49) {
        v = -1e30f;
      } else {
        float bi = 0.f, mk = 0.f;
        if (m < 49) {
          int rm = m / 7, cm = m % 7, rj = j / 7, cj = j % 7;
          int rpi = (rm - rj + 6) * 13 + (cm - cj + 6);
          bi = bias_table[rpi * 8 + h];
          mk = mask[((size_t)w * 49 + m) * 49 + j];
        }
        v = (mk + bi) * LOG2E;
      }
      dst[idx] = v;
    }
  } else {  // qkv bias: q part prescaled
    float* dst = (float*)(ws + WS_QB);
    for (int i = tid; i < 768; i += 256)
      dst[i] = qkv_b[i] * (i < 256 ? QSCALE * LOG2E : 1.f);
  }
}

// One block = one window, 4 waves (256 thr), 4 passes of 2 heads.
// Wave wv: head-slot hs = wv>>1, m-half s = wv&1; pass p: head h = 2p + hs.
// x fragments in REGISTERS (xf[2][8]); ONE barrier per pass (R15 induction).
// R18 final form (twice-verified 299.7/299.9 us): split-K Phase B (2
// independent 4-deep MFMA chains) + dual bufP slots (QK+exp2+stores for
// both i batched before the pf reads). launch_bounds(256,2): no spill.
// LDS 79.5 KiB -> 2 blocks/CU (2x81408 = 159K <= 160K).
//  [0,32K)   aoR: ao[m<49][256ch] bf16, byte = m*512 + (2c ^ ((m&7)<<4));
//            rows 50..63 host per-wave bufPA = 25600 + wv*1152
//  q:  32768 + hs*4608            ([64m][32d] stride 72, wave-private rows)
//  k:  41984 + (2hs+par)*4608     ([64m][32d] stride 72)
//  vT: 60416 + (2hs+par)*4096     ([32d][64tok] stride 128)
//  bufPB: 76800 + wv*1152         (second P slot, [16m][32j] stride 72)
__global__ __launch_bounds__(256, 2)
void winattn_main(const float* __restrict__ x,
                  const unsigned char* __restrict__ ws,
                  const float* __restrict__ proj_b,
                  float* __restrict__ out) {
  __shared__ __align__(16) unsigned char lds[81408];
  const int tid = threadIdx.x;
  const int wv = tid >> 6, ln = tid & 63;
  const int lr = ln & 15, lg = ln >> 4;
  const int b = blockIdx.x;
  const int w = b & 63;
  const int hs = wv >> 1, s = wv & 1;
  const float* qbs = (const float*)(ws + WS_QB);
  unsigned char* aoR = lds;
  unsigned char* bufPA = lds + 25600 + wv * 1152;  // aoR rows 50..63
  unsigned char* bufPB = lds + 76800 + wv * 1152;
  unsigned char* qbuf = lds + 32768 + hs * 4608;

  // ---- x fragments -> registers (held for entire kernel); rows >= 49 zero
  bf16x8 xf[2][8];
#pragma unroll
  for (int ti = 0; ti < 2; ++ti) {
    const int row = 16 * (2 * s + ti) + lr;
    const float* xr = x + ((size_t)b * 49 + row) * 256 + 8 * lg;
    const bool val = (row < 49);
#pragma unroll
    for (int ks = 0; ks < 8; ++ks) {
      f32x4 va = {0.f, 0.f, 0.f, 0.f}, vb = {0.f, 0.f, 0.f, 0.f};
      if (val) {
        va = *(const f32x4*)(xr + 32 * ks);
        vb = *(const f32x4*)(xr + 32 * ks + 4);
      }
      u64x2 t2 = {pack4bf(va), pack4bf(vb)};
      xf[ti][ks] = __builtin_bit_cast(bf16x8, t2);
    }
  }

  for (int p = 0; p < 4; ++p) {
    const int par = p & 1;
    unsigned char* kbuf = lds + 41984 + (2 * hs + par) * 4608;
    unsigned char* vbuf = lds + 60416 + (2 * hs + par) * 4096;
    const int h = 2 * p + hs;
    const float* mbp = (const float*)(ws + WS_MB) + ((size_t)(w * 8 + h)) * 4096;

    // ---- prefetch mb rows for Phase C (latency hides under Phase B MFMAs)
    f32x4 mkr[4][2];
#pragma unroll
    for (int i = 0; i < 2; ++i) {
      const int m = lr + 32 * s + 16 * i;
#pragma unroll
      for (int jt = 0; jt < 4; ++jt)
        mkr[jt][i] = *(const f32x4*)(mbp + m * 64 + 16 * jt + 4 * lg);
    }

    // ---- Phase B: weight groups g=0..5 (q0,q1,k0,k1,v0,v1), double-buffered
    bf16x8 afb[2][8];
#pragma unroll
    for (int ks = 0; ks < 8; ++ks)
      afb[0][ks] = *(const bf16x8*)(ws + (size_t)((2 * h) * 8 + ks) * 1024 + ln * 16);

    // q,k groups (g = 0..3); split-K: two independent 4-deep chains per ti
#pragma unroll
    for (int g = 0; g < 4; ++g) {
      const int pp = g >> 1, g2 = g & 1;
      {  // prefetch group g+1
        const int gn = g + 1;
        const int rtn = 16 * (gn >> 1) + 2 * h + (gn & 1);
#pragma unroll
        for (int ks = 0; ks < 8; ++ks)
          afb[gn & 1][ks] = *(const bf16x8*)(ws + (size_t)(rtn * 8 + ks) * 1024 + ln * 16);
      }
      f32x4 cc = *(const f32x4*)(qbs + pp * 256 + 32 * h + 16 * g2 + 4 * lg);
      unsigned char* dst = (pp == 0 ? qbuf : kbuf);
#pragma unroll
      for (int ti = 0; ti < 2; ++ti) {
        const int row = 16 * (2 * s + ti) + lr;
        f32x4 a0 = cc, a1 = {0.f, 0.f, 0.f, 0.f};
#pragma unroll
        for (int kk = 0; kk < 4; ++kk) {
          a0 = __builtin_amdgcn_mfma_f32_16x16x32_bf16(afb[g & 1][kk], xf[ti][kk], a0, 0, 0, 0);
          a1 = __builtin_amdgcn_mfma_f32_16x16x32_bf16(afb[g & 1][kk + 4], xf[ti][kk + 4], a1, 0, 0, 0);
        }
        a0 += a1;
        *(unsigned long long*)(dst + row * 72 + 32 * g2 + 8 * lg) = pack4bf(a0);
      }
    }
    bf16x8 qf[2];
#pragma unroll
    for (int i = 0; i < 2; ++i)  // own rows (wave-private) -> no barrier
      qf[i] = *(const bf16x8*)(qbuf + (lr + 32 * s + 16 * i) * 72 + 16 * lg);

    // v groups (g = 4,5) -> vT into vbuf; same split-K
#pragma unroll
    for (int g = 4; g < 6; ++g) {
      const int g2 = g & 1;
      if (g < 5) {  // prefetch group 5
#pragma unroll
        for (int ks = 0; ks < 8; ++ks)
          afb[1][ks] = *(const bf16x8*)(ws + (size_t)((32 + 2 * h + 1) * 8 + ks) * 1024 + ln * 16);
      }
      const float vb = qbs[512 + 32 * h + 16 * g2 + lr];
      f32x4 cc = {vb, vb, vb, vb};
#pragma unroll
      for (int ti = 0; ti < 2; ++ti) {
        const int t = 2 * s + ti;
        f32x4 a0 = cc, a1 = {0.f, 0.f, 0.f, 0.f};
#pragma unroll
        for (int kk = 0; kk < 4; ++kk) {
          a0 = __builtin_amdgcn_mfma_f32_16x16x32_bf16(xf[ti][kk], afb[g & 1][kk], a0, 0, 0, 0);
          a1 = __builtin_amdgcn_mfma_f32_16x16x32_bf16(xf[ti][kk + 4], afb[g & 1][kk + 4], a1, 0, 0, 0);
        }
        a0 += a1;
        const int d = 16 * g2 + lr;
        *(unsigned long long*)(vbuf + d * 128 + ((32 * t + 8 * lg) ^ ((d & 7) << 4))) =
            pack4bf(a0);
      }
    }
    __syncthreads();  // the ONE barrier: k + vT staged pair-wide
    bf16x8 kf[4];
#pragma unroll
    for (int t = 0; t < 4; ++t)
      kf[t] = *(const bf16x8*)(kbuf + (lr + 16 * t) * 72 + 16 * lg);

    // ---- Phase C: batched QK->stores (both i, dual bufP), then both PV
    float sm[2] = {0.f, 0.f};
    f32x4 oacc[2][2];
#pragma unroll
    for (int dt = 0; dt < 2; ++dt)
#pragma unroll
      for (int i = 0; i < 2; ++i) oacc[dt][i] = {0.f, 0.f, 0.f, 0.f};
#pragma unroll
    for (int jh = 0; jh < 2; ++jh) {
      bf16x8 vf[2];
#pragma unroll
      for (int dt = 0; dt < 2; ++dt) {
        const int d = lr + 16 * dt;
        vf[dt] = *(const bf16x8*)(vbuf + d * 128 + ((64 * jh + 16 * lg) ^ ((d & 7) << 4)));
      }
#pragma unroll
      for (int i = 0; i < 2; ++i) {
        unsigned char* bp = (i == 0) ? bufPA : bufPB;
#pragma unroll
        for (int jt2 = 0; jt2 < 2; ++jt2) {
          const int jt = 2 * jh + jt2;
          f32x4 sv = __builtin_amdgcn_mfma_f32_16x16x32_bf16(kf[jt], qf[i], mkr[jt][i], 0, 0, 0);
#pragma unroll
          for (int r2 = 0; r2 < 4; ++r2) {
            float e = __builtin_amdgcn_exp2f(sv[r2]);
            sv[r2] = e;
            sm[i] += e;
          }
          *(unsigned long long*)(bp + lr * 72 + 32 * jt2 + 8 * lg) = pack4bf(sv);
        }
      }
#pragma unroll
      for (int i = 0; i < 2; ++i) {
        unsigned char* bp = (i == 0) ? bufPA : bufPB;
        bf16x8 pf = *(const bf16x8*)(bp + lr * 72 + 16 * lg);
#pragma unroll
        for (int dt = 0; dt < 2; ++dt)
          oacc[dt][i] = __builtin_amdgcn_mfma_f32_16x16x32_bf16(vf[dt], pf, oacc[dt][i], 0, 0, 0);
      }
    }
    // normalize + write ao (rows m<49 only; rows 50..63 host bufPA)
#pragma unroll
    for (int i = 0; i < 2; ++i) {
      float t = sm[i];
      t += __shfl_xor(t, 16);
      t += __shfl_xor(t, 32);
      const float inv = 1.f / t;
      const int m = lr + 32 * s + 16 * i;
      if (m < 49) {
#pragma unroll
        for (int dt = 0; dt < 2; ++dt)
          *(unsigned long long*)(aoR + m * 512 +
                                 ((64 * h + 32 * dt + 8 * lg) ^ ((m & 7) << 4))) =
              pack4bf(oacc[dt][i] * inv);
      }
    }
  }
  __syncthreads();  // all heads' ao staged

  // ---- Phase D: proj^T[o][m] = sum_c Wp[o][c] * ao[m][c]
  // i2-outer: 4 weight-tile loads (double-buffered); aof from LDS
  const unsigned char* wsP = ws + WS_PROJ;
  bf16x8 afD[2][8];
#pragma unroll
  for (int ks = 0; ks < 8; ++ks)
    afD[0][ks] = *(const bf16x8*)(wsP + (size_t)((4 * wv) * 8 + ks) * 1024 + ln * 16);
#pragma unroll
  for (int i2 = 0; i2 < 4; ++i2) {
    const int mt = 4 * wv + i2;
    if (i2 < 3) {
#pragma unroll
      for (int ks = 0; ks < 8; ++ks)
        afD[(i2 + 1) & 1][ks] =
            *(const bf16x8*)(wsP + (size_t)((mt + 1) * 8 + ks) * 1024 + ln * 16);
    }
    const f32x4 pb = *(const f32x4*)(proj_b + 16 * mt + 4 * lg);
#pragma unroll
    for (int tt = 0; tt < 4; ++tt) {
      const int m = lr + 16 * tt;
      f32x4 acc = {0.f, 0.f, 0.f, 0.f};
#pragma unroll
      for (int ks = 0; ks < 8; ++ks) {
        bf16x8 aof = *(const bf16x8*)(aoR + m * 512 + ((64 * ks + 16 * lg) ^ ((m & 7) << 4)));
        acc = __builtin_amdgcn_mfma_f32_16x16x32_bf16(afD[i2 & 1][ks], aof, acc, 0, 0, 0);
      }
      if (m < 49) {
        *(f32x4*)(out + ((size_t)b * 49 + m) * 256 + 16 * mt + 4 * lg) = acc + pb;
      }
    }
  }
}

extern "C" void kernel_launch(void* const* d_in, const int* in_sizes, int n_in,
                              void* d_out, int out_size, void* d_ws, size_t ws_size,
                              hipStream_t stream) {
  const float* x = (const float*)d_in[0];
  const float* mask = (const float*)d_in[1];
  const float* qkv_w = (const float*)d_in[2];
  const float* qkv_b = (const float*)d_in[3];
  const float* proj_w = (const float*)d_in[4];
  const float* proj_b = (const float*)d_in[5];
  const float* bias_table = (const float*)d_in[6];
  unsigned char* ws = (unsigned char*)d_ws;
  float* out = (float*)d_out;

  prep_weights<<<512, 64, 0, stream>>>(qkv_w, proj_w, ws);
  prep_aux<<<513, 256, 0, stream>>>(mask, bias_table, qkv_b, ws);
  winattn_main<<<4096, 256, 0, stream>>>(x, ws, proj_b, out);
}